// Round 5
// baseline (144.818 us; speedup 1.0000x reference)
//
#include <hip/hip_runtime.h>
#include <hip/hip_cooperative_groups.h>
#include <math.h>

namespace cg = cooperative_groups;

#define B 256
#define S 512
#define H 768
#define H4 (H / 4)      // 192 float4 columns
#define NSMALL 64       // n = B/4

__device__ __forceinline__ float waveReduceSum(float v) {
    v += __shfl_down(v, 32);
    v += __shfl_down(v, 16);
    v += __shfl_down(v, 8);
    v += __shfl_down(v, 4);
    v += __shfl_down(v, 2);
    v += __shfl_down(v, 1);
    return v;
}

// One cooperative kernel, 256 blocks x 768 threads (1 block/CU, 12 waves).
// Phase A: block b mean-pools batch b's 512x768 slab (coalesced float4
//          streams, LDS row-group reduce, mask-sum divide, L2-normalize)
//          and writes z[b].
// grid.sync()
// Phase B: block = (row i = blk>>2, col-chunk jc = blk&3). 12 waves x 64
//          cols compute 64-elem partial dots, LDS-combine to 64 full dots;
//          wave 0 does exp-sum (logits in [-2,2]: no max needed) and the
//          jc==0 pair-term partial.
// grid.sync()
// Phase C: block 0 wave 0: rowloss_i = (63-i)*log(sum_c sp) + pairneg_i,
//          reduce, scale, write out.
__global__ void __launch_bounds__(768) fused_k(const float* __restrict__ lhs,
                                               const float* __restrict__ mask,
                                               float* __restrict__ z,
                                               float* __restrict__ sp,
                                               float* __restrict__ pairneg,
                                               float* __restrict__ out) {
    cg::grid_group grid = cg::this_grid();
    const int blk = blockIdx.x;     // 0..255
    const int t   = threadIdx.x;    // 0..767

    __shared__ __align__(16) float smem[2320];

    // ---------------- Phase A: pool + normalize -> z[blk] ----------------
    {
        const int col = t % H4;     // float4 column
        const int rg  = t / H4;     // row-group 0..3 (192 = 3 waves each)
        float4* red = reinterpret_cast<float4*>(smem);   // [3][H4]
        float*  sm  = smem + 3 * H4 * 4;                 // 12 mask wave-sums
        float*  sq  = sm + 12;                           // 3 sumsq wave-sums

        const float4* __restrict__ src =
            reinterpret_cast<const float4*>(lhs) + (size_t)blk * S * H4;
        float4 acc = make_float4(0.f, 0.f, 0.f, 0.f);
#pragma unroll 8
        for (int s = 0; s < S / 4; ++s) {
            float4 v = src[(size_t)(4 * s + rg) * H4 + col];
            acc.x += v.x; acc.y += v.y; acc.z += v.z; acc.w += v.w;
        }
        if (rg > 0) red[(rg - 1) * H4 + col] = acc;

        // mask.sum over 512 tokens (threads 0..511; waves 8..11 give 0)
        float mv = (t < S) ? mask[(size_t)blk * S + t] : 0.f;
        float w = waveReduceSum(mv);
        if ((t & 63) == 0) sm[t >> 6] = w;
        __syncthreads();

        float msum = 0.f;
#pragma unroll
        for (int k = 0; k < 12; ++k) msum += sm[k];

        float4 p = acc;
        if (rg == 0) {
            float4 r0 = red[0 * H4 + col];
            float4 r1 = red[1 * H4 + col];
            float4 r2 = red[2 * H4 + col];
            p.x += r0.x + r1.x + r2.x;
            p.y += r0.y + r1.y + r2.y;
            p.z += r0.z + r1.z + r2.z;
            p.w += r0.w + r1.w + r2.w;
            const float inv_m = 1.0f / msum;
            p.x *= inv_m; p.y *= inv_m; p.z *= inv_m; p.w *= inv_m;
            float s2 = p.x * p.x + p.y * p.y + p.z * p.z + p.w * p.w;
            float ws2 = waveReduceSum(s2);   // waves 0..2 are full
            if ((t & 63) == 0) sq[t >> 6] = ws2;
        }
        __syncthreads();
        if (rg == 0) {
            const float inv_n = 1.0f / sqrtf(sq[0] + sq[1] + sq[2]);
            float4 zp = make_float4(p.x * inv_n, p.y * inv_n,
                                    p.z * inv_n, p.w * inv_n);
            reinterpret_cast<float4*>(z + (size_t)blk * H)[col] = zp;
        }
    }

    grid.sync();

    // ---------------- Phase B: per-(row, col-chunk) partials ----------------
    {
        const int i   = blk >> 2;   // 0..63
        const int jc  = blk & 3;    // 0..3
        const int col = t & 63;
        const int q   = t >> 6;     // 0..11 (one wave per q)
        const int j   = jc * 64 + col;

        float* zi = smem;           // 768
        float* pd = smem + H;       // 12 * 64

        zi[t] = z[(size_t)i * H + t];
        __syncthreads();

        // partial dot over elems q*64 .. q*64+63 (16 float4)
        const float4* __restrict__ zj4 =
            reinterpret_cast<const float4*>(z + (size_t)j * H) + q * 16;
        const float4* zi4 = reinterpret_cast<const float4*>(zi) + q * 16;
        float d0 = 0.f, d1 = 0.f;
#pragma unroll
        for (int k = 0; k < 16; k += 2) {
            float4 a  = zi4[k];     float4 c1 = zj4[k];
            float4 a2 = zi4[k + 1]; float4 c2 = zj4[k + 1];
            d0 += a.x * c1.x + a.y * c1.y + a.z * c1.z + a.w * c1.w;
            d1 += a2.x * c2.x + a2.y * c2.y + a2.z * c2.z + a2.w * c2.w;
        }
        pd[q * 64 + col] = d0 + d1;
        __syncthreads();

        if (t < 64) {   // wave 0 finalizes; here col == t, j = jc*64 + t
            float dot = 0.f;
#pragma unroll
            for (int q2 = 0; q2 < 12; ++q2) dot += pd[q2 * 64 + t];
            const float logit = dot * 2.0f;   // / TAU
            const float ev = (j == i) ? 0.f : expf(logit);
            float s = waveReduceSum(ev);
            if (t == 0) sp[i * 4 + jc] = s;
            if (jc == 0) {
                const float term = (t > i) ? -logit : 0.f;
                float ts = waveReduceSum(term);
                if (t == 0) pairneg[i] = ts;
            }
        }
    }

    grid.sync();

    // ---------------- Phase C: final reduction ----------------
    if (blk == 0 && t < 64) {
        const int i = t;
        const float s = sp[i * 4] + sp[i * 4 + 1] + sp[i * 4 + 2] + sp[i * 4 + 3];
        const float row = (float)(NSMALL - 1 - i) * logf(s) + pairneg[i];
        float tot = waveReduceSum(row);
        if (t == 0) {
            out[0] = (-2.0f / (float)NSMALL) * (float)(NSMALL - 1) * tot;
        }
    }
}

extern "C" void kernel_launch(void* const* d_in, const int* in_sizes, int n_in,
                              void* d_out, int out_size, void* d_ws, size_t ws_size,
                              hipStream_t stream) {
    const float* lhs  = (const float*)d_in[0];   // [256,512,768] f32
    const float* mask = (const float*)d_in[1];   // [256,512] f32
    float* out = (float*)d_out;                  // scalar f32
    float* ws  = (float*)d_ws;

    float* z       = ws;                         // B*H = 196,608 f
    float* sp      = z + (size_t)B * H;          // 64*4 = 256 f
    float* pairneg = sp + NSMALL * 4;            // 64 f

    void* args[] = { (void*)&lhs, (void*)&mask, (void*)&z,
                     (void*)&sp, (void*)&pairneg, (void*)&out };
    hipLaunchCooperativeKernel(reinterpret_cast<void*>(fused_k),
                               dim3(B), dim3(H), args, 0, stream);
}

// Round 6
// 88.340 us; speedup vs baseline: 1.6393x; 1.6393x over previous
//
#include <hip/hip_runtime.h>
#include <math.h>

#define B 256
#define S 512
#define H 768
#define H4 (H / 4)      // 192 float4 columns
#define NSMALL 64       // n = B/4

__device__ __forceinline__ float waveReduceSum(float v) {
    v += __shfl_down(v, 32);
    v += __shfl_down(v, 16);
    v += __shfl_down(v, 8);
    v += __shfl_down(v, 4);
    v += __shfl_down(v, 2);
    v += __shfl_down(v, 1);
    return v;
}

// Kernel 1: one block per batch. 768 threads = 192 float4-cols x 4 row-groups.
// Streams the batch's 512x768 slab (1.57 MB) coalesced (each wave: 1 KB
// contiguous per load), LDS-reduces the 4 row-groups, applies mask-sum
// division and L2 normalization in-block, writes z[b] directly.
// Also zeroes the epilogue's completion counter (stream order guarantees
// it is 0 before kernel 2 starts; kernel 2's last block consumed it).
__global__ void pool_z_k(const float* __restrict__ lhs,
                         const float* __restrict__ mask,
                         float* __restrict__ z,
                         unsigned int* __restrict__ counter) {
    const int b = blockIdx.x;       // 0..255
    const int t = threadIdx.x;      // 0..767

    if (b == 0 && t == 0) *counter = 0;

    const int col = t % H4;         // float4 column
    const int rg  = t / H4;         // row-group 0..3 (wave-aligned: 192 = 3*64)

    __shared__ float4 red[3][H4];   // rg 1..3 partials
    __shared__ float sm[12];        // mask wave sums
    __shared__ float sq[3];         // sumsq wave sums

    const float4* __restrict__ src =
        reinterpret_cast<const float4*>(lhs) + (size_t)b * S * H4;
    float4 acc = make_float4(0.f, 0.f, 0.f, 0.f);
#pragma unroll 8
    for (int s = 0; s < S / 4; ++s) {
        float4 v = src[(size_t)(4 * s + rg) * H4 + col];
        acc.x += v.x; acc.y += v.y; acc.z += v.z; acc.w += v.w;
    }
    if (rg > 0) red[rg - 1][col] = acc;

    // mask.sum over 512 tokens (threads 0..511; waves 8..11 contribute 0)
    float mv = (t < S) ? mask[(size_t)b * S + t] : 0.f;
    float w = waveReduceSum(mv);
    if ((t & 63) == 0) sm[t >> 6] = w;
    __syncthreads();

    float msum = 0.f;
#pragma unroll
    for (int k = 0; k < 12; ++k) msum += sm[k];

    float4 p = acc;
    if (rg == 0) {
        float4 r0 = red[0][col], r1 = red[1][col], r2 = red[2][col];
        p.x += r0.x + r1.x + r2.x;
        p.y += r0.y + r1.y + r2.y;
        p.z += r0.z + r1.z + r2.z;
        p.w += r0.w + r1.w + r2.w;
        const float inv_m = 1.0f / msum;
        p.x *= inv_m; p.y *= inv_m; p.z *= inv_m; p.w *= inv_m;
        float s2 = p.x * p.x + p.y * p.y + p.z * p.z + p.w * p.w;
        float ws2 = waveReduceSum(s2);          // waves 0..2 full
        if ((t & 63) == 0) sq[t >> 6] = ws2;
    }
    __syncthreads();
    if (rg == 0) {
        const float inv_n = 1.0f / sqrtf(sq[0] + sq[1] + sq[2]);
        float4 zp = make_float4(p.x * inv_n, p.y * inv_n, p.z * inv_n, p.w * inv_n);
        reinterpret_cast<float4*>(z + (size_t)b * H)[col] = zp;
    }
}

// Kernel 2 (fused epilogue): 256 blocks = (row i 0..63) x (col-chunk jc 0..3).
// Thread t: column col = t&63 (global j = jc*64+col), quarter q = t>>6.
// Each thread computes a 192-elem partial dot; LDS-combine to full dots.
// logits in [-2,2] -> exp without max-subtraction is safe (sum <= 255*e^2).
// Block writes sp[i*4+jc] = sum_j exp(logit_ij) (diag masked); jc==0 also
// writes pairneg[i] = sum_{j>i,j<64} (-logit_ij). The LAST block to finish
// (device-scope counter) runs the final reduction and writes out.
__global__ void row_loss_fused_k(const float* __restrict__ z,
                                 float* __restrict__ sp,
                                 float* __restrict__ pairneg,
                                 unsigned int* __restrict__ counter,
                                 float* __restrict__ out) {
    const int i  = blockIdx.x >> 2;
    const int jc = blockIdx.x & 3;
    const int t  = threadIdx.x;    // 0..255
    const int col = t & 63;
    const int q   = t >> 6;
    const int j   = jc * 64 + col;

    __shared__ float zi[H];
    __shared__ float pd[4][64];
    __shared__ bool isLast;

    zi[t]       = z[(size_t)i * H + t];
    zi[t + 256] = z[(size_t)i * H + 256 + t];
    zi[t + 512] = z[(size_t)i * H + 512 + t];
    __syncthreads();

    // partial dot: elems q*192 .. q*192+191 (48 float4)
    const float4* __restrict__ zj4 =
        reinterpret_cast<const float4*>(z + (size_t)j * H) + q * 48;
    const float4* zi4 = reinterpret_cast<const float4*>(zi) + q * 48;
    float d0 = 0.f, d1 = 0.f;
#pragma unroll 8
    for (int k = 0; k < 48; k += 2) {
        float4 a  = zi4[k];     float4 c1 = zj4[k];
        float4 a2 = zi4[k + 1]; float4 c2 = zj4[k + 1];
        d0 += a.x * c1.x + a.y * c1.y + a.z * c1.z + a.w * c1.w;
        d1 += a2.x * c2.x + a2.y * c2.y + a2.z * c2.z + a2.w * c2.w;
    }
    pd[q][col] = d0 + d1;
    __syncthreads();

    if (t < 64) {  // wave 0 finalizes; col == t here
        const float dot = pd[0][t] + pd[1][t] + pd[2][t] + pd[3][t];
        const float logit = dot * 2.0f;  // / TAU
        const float ev = (j == i) ? 0.f : expf(logit);
        float s = waveReduceSum(ev);
        if (t == 0) sp[i * 4 + jc] = s;
        if (jc == 0) {
            const float term = (t > i) ? -logit : 0.f;
            float ts = waveReduceSum(term);
            if (t == 0) pairneg[i] = ts;
        }
    }

    // last-block-done: thread 0 publishes, last arriver runs the final pass
    if (t == 0) {
        __threadfence();                       // sp/pairneg visible device-wide
        unsigned int prev = atomicAdd(counter, 1u);
        isLast = (prev == (unsigned int)(4 * NSMALL - 1));
    }
    __syncthreads();

    if (isLast) {
        __threadfence();                       // acquire all blocks' writes
        if (t < 64) {
            const int r = t;
            const float s = sp[r * 4] + sp[r * 4 + 1] + sp[r * 4 + 2] + sp[r * 4 + 3];
            const float row = (float)(NSMALL - 1 - r) * logf(s) + pairneg[r];
            float tot = waveReduceSum(row);
            if (t == 0) {
                out[0] = (-2.0f / (float)NSMALL) * (float)(NSMALL - 1) * tot;
            }
        }
    }
}

extern "C" void kernel_launch(void* const* d_in, const int* in_sizes, int n_in,
                              void* d_out, int out_size, void* d_ws, size_t ws_size,
                              hipStream_t stream) {
    const float* lhs  = (const float*)d_in[0];   // [256,512,768] f32
    const float* mask = (const float*)d_in[1];   // [256,512] f32
    float* out = (float*)d_out;                  // scalar f32
    float* ws  = (float*)d_ws;

    float* z            = ws;                    // B*H = 196,608 f
    float* sp           = z + (size_t)B * H;     // 64*4 = 256 f
    float* pairneg      = sp + NSMALL * 4;       // 64 f
    unsigned int* cnt   = (unsigned int*)(pairneg + NSMALL);  // 1 u32

    pool_z_k<<<B, H, 0, stream>>>(lhs, mask, z, cnt);
    row_loss_fused_k<<<NSMALL * 4, 256, 0, stream>>>(z, sp, pairneg, cnt, out);
}

// Round 7
// 75.052 us; speedup vs baseline: 1.9296x; 1.1771x over previous
//
#include <hip/hip_runtime.h>
#include <math.h>

#define B 256
#define S 512
#define H 768
#define H4 (H / 4)      // 192 float4 columns
#define NSMALL 64       // n = B/4

typedef float f32x4 __attribute__((ext_vector_type(4)));

__device__ __forceinline__ float waveReduceSum(float v) {
    v += __shfl_down(v, 32);
    v += __shfl_down(v, 16);
    v += __shfl_down(v, 8);
    v += __shfl_down(v, 4);
    v += __shfl_down(v, 2);
    v += __shfl_down(v, 1);
    return v;
}

// Kernel 1: one block per batch. 768 threads = 192 float4-cols x 4 row-groups.
// Streams the batch's 512x768 slab (1.57 MB) coalesced with NON-TEMPORAL
// loads (zero-reuse data: don't allocate L1/L2 lines), LDS-reduces the 4
// row-groups, applies mask-sum division and L2 normalization in-block,
// writes z[b] directly.
__global__ void pool_z_k(const float* __restrict__ lhs,
                         const float* __restrict__ mask,
                         float* __restrict__ z) {
    const int b = blockIdx.x;       // 0..255
    const int t = threadIdx.x;      // 0..767
    const int col = t % H4;         // float4 column
    const int rg  = t / H4;         // row-group 0..3 (wave-aligned: 192 = 3*64)

    __shared__ f32x4 red[3][H4];    // rg 1..3 partials
    __shared__ float sm[12];        // mask wave sums
    __shared__ float sq[3];         // sumsq wave sums

    const f32x4* __restrict__ src =
        reinterpret_cast<const f32x4*>(lhs) + (size_t)b * S * H4;
    f32x4 acc = {0.f, 0.f, 0.f, 0.f};
#pragma unroll 8
    for (int s = 0; s < S / 4; ++s) {
        f32x4 v = __builtin_nontemporal_load(&src[(size_t)(4 * s + rg) * H4 + col]);
        acc += v;
    }
    if (rg > 0) red[rg - 1][col] = acc;

    // mask.sum over 512 tokens (threads 0..511; waves 8..11 contribute 0)
    float mv = (t < S) ? __builtin_nontemporal_load(&mask[(size_t)b * S + t]) : 0.f;
    float w = waveReduceSum(mv);
    if ((t & 63) == 0) sm[t >> 6] = w;
    __syncthreads();

    float msum = 0.f;
#pragma unroll
    for (int k = 0; k < 12; ++k) msum += sm[k];

    f32x4 p = acc;
    if (rg == 0) {
        p += red[0][col];
        p += red[1][col];
        p += red[2][col];
        const float inv_m = 1.0f / msum;
        p *= inv_m;
        float s2 = p.x * p.x + p.y * p.y + p.z * p.z + p.w * p.w;
        float ws2 = waveReduceSum(s2);          // waves 0..2 full
        if ((t & 63) == 0) sq[t >> 6] = ws2;
    }
    __syncthreads();
    if (rg == 0) {
        const float inv_n = 1.0f / sqrtf(sq[0] + sq[1] + sq[2]);
        p *= inv_n;
        reinterpret_cast<f32x4*>(z + (size_t)b * H)[col] = p;
    }
}

// Kernel 2: 256 blocks = (row i 0..63) x (col-chunk jc 0..3 of 64 cols).
// Thread t: column col = t&63 (global j = jc*64+col), quarter q = t>>6.
// Each thread computes a 192-elem partial dot; LDS-combine to full dots.
// logits in [-2,2] -> exp without max-subtraction is safe (sum <= 255*e^2).
// Block writes: sp[i*4+jc] = sum_j exp(logit_ij) (diag masked);
// jc==0 also writes pairneg[i] = sum_{j>i,j<64} (-logit_ij).
__global__ void row_part_k(const float* __restrict__ z,
                           float* __restrict__ sp,
                           float* __restrict__ pairneg) {
    const int i  = blockIdx.x >> 2;
    const int jc = blockIdx.x & 3;
    const int t  = threadIdx.x;    // 0..255
    const int col = t & 63;
    const int q   = t >> 6;
    const int j   = jc * 64 + col;

    __shared__ float zi[H];
    __shared__ float pd[4][64];

    zi[t]       = z[(size_t)i * H + t];
    zi[t + 256] = z[(size_t)i * H + 256 + t];
    zi[t + 512] = z[(size_t)i * H + 512 + t];
    __syncthreads();

    // partial dot: elems q*192 .. q*192+191 (48 float4)
    const float4* __restrict__ zj4 =
        reinterpret_cast<const float4*>(z + (size_t)j * H) + q * 48;
    const float4* zi4 = reinterpret_cast<const float4*>(zi) + q * 48;
    float d0 = 0.f, d1 = 0.f;
#pragma unroll 8
    for (int k = 0; k < 48; k += 2) {
        float4 a  = zi4[k];     float4 c1 = zj4[k];
        float4 a2 = zi4[k + 1]; float4 c2 = zj4[k + 1];
        d0 += a.x * c1.x + a.y * c1.y + a.z * c1.z + a.w * c1.w;
        d1 += a2.x * c2.x + a2.y * c2.y + a2.z * c2.z + a2.w * c2.w;
    }
    pd[q][col] = d0 + d1;
    __syncthreads();

    if (t < 64) {  // wave 0 finalizes; col == t here
        const float dot = pd[0][t] + pd[1][t] + pd[2][t] + pd[3][t];
        const float logit = dot * 2.0f;  // / TAU
        const float ev = (j == i) ? 0.f : expf(logit);
        float s = waveReduceSum(ev);
        if (t == 0) sp[i * 4 + jc] = s;
        if (jc == 0) {
            const float term = (t > i) ? -logit : 0.f;
            float ts = waveReduceSum(term);
            if (t == 0) pairneg[i] = ts;
        }
    }
}

// Kernel 3: one wave. rowloss_i = (63-i)*log(sum_c sp[i][c]) + pairneg[i].
__global__ void final_k(const float* __restrict__ sp,
                        const float* __restrict__ pairneg,
                        float* __restrict__ out) {
    const int i = threadIdx.x;  // 0..63
    const float s = sp[i * 4] + sp[i * 4 + 1] + sp[i * 4 + 2] + sp[i * 4 + 3];
    const float logden = logf(s);
    const float row = (float)(NSMALL - 1 - i) * logden + pairneg[i];
    float tot = waveReduceSum(row);
    if (i == 0) {
        out[0] = (-2.0f / (float)NSMALL) * (float)(NSMALL - 1) * tot;
    }
}

extern "C" void kernel_launch(void* const* d_in, const int* in_sizes, int n_in,
                              void* d_out, int out_size, void* d_ws, size_t ws_size,
                              hipStream_t stream) {
    const float* lhs  = (const float*)d_in[0];   // [256,512,768] f32
    const float* mask = (const float*)d_in[1];   // [256,512] f32
    float* out = (float*)d_out;                  // scalar f32
    float* ws  = (float*)d_ws;

    float* z       = ws;                         // B*H = 196,608 f
    float* sp      = z + (size_t)B * H;          // 64*4 = 256 f
    float* pairneg = sp + NSMALL * 4;            // 64 f

    pool_z_k<<<B, H, 0, stream>>>(lhs, mask, z);
    row_part_k<<<NSMALL * 4, 256, 0, stream>>>(z, sp, pairneg);
    final_k<<<1, 64, 0, stream>>>(sp, pairneg, out);
}

// Round 8
// 73.326 us; speedup vs baseline: 1.9750x; 1.0235x over previous
//
#include <hip/hip_runtime.h>
#include <math.h>

#define B 256
#define S 512
#define H 768
#define H4 (H / 4)      // 192 float4 columns
#define NSMALL 64       // n = B/4

typedef float f32x4 __attribute__((ext_vector_type(4)));

__device__ __forceinline__ float waveReduceSum(float v) {
    v += __shfl_down(v, 32);
    v += __shfl_down(v, 16);
    v += __shfl_down(v, 8);
    v += __shfl_down(v, 4);
    v += __shfl_down(v, 2);
    v += __shfl_down(v, 1);
    return v;
}

// Kernel 1: one block per batch. 768 threads = 192 float4-cols x 4 row-groups.
// Streams the batch's 512x768 slab (1.57 MB) coalesced with NON-TEMPORAL
// loads (zero-reuse data), LDS-reduces the 4 row-groups, L2-normalizes,
// writes z[b].
// NOTE: the input mask cancels algebraically: z = (sum/m)/|sum/m| = sum/|sum|,
// and the loss depends only on z — so the mask is never read and the division
// is skipped (identical math, fewer ops, one less sync).
__global__ void pool_z_k(const float* __restrict__ lhs,
                         float* __restrict__ z) {
    const int b = blockIdx.x;       // 0..255
    const int t = threadIdx.x;      // 0..767
    const int col = t % H4;         // float4 column
    const int rg  = t / H4;         // row-group 0..3 (wave-aligned: 192 = 3*64)

    __shared__ f32x4 red[3][H4];    // rg 1..3 partials
    __shared__ float sq[3];         // sumsq wave sums (waves 0..2)

    const f32x4* __restrict__ src =
        reinterpret_cast<const f32x4*>(lhs) + (size_t)b * S * H4;
    f32x4 acc = {0.f, 0.f, 0.f, 0.f};
#pragma unroll 16
    for (int s = 0; s < S / 4; ++s) {
        f32x4 v = __builtin_nontemporal_load(&src[(size_t)(4 * s + rg) * H4 + col]);
        acc += v;
    }
    if (rg > 0) red[rg - 1][col] = acc;
    __syncthreads();

    if (rg == 0) {
        f32x4 p = acc;
        p += red[0][col];
        p += red[1][col];
        p += red[2][col];
        float s2 = p.x * p.x + p.y * p.y + p.z * p.z + p.w * p.w;
        float ws2 = waveReduceSum(s2);          // waves 0..2 full
        if ((t & 63) == 0) sq[t >> 6] = ws2;
        __builtin_amdgcn_s_barrier();           // only waves 0..2 needed; full
                                                // barrier keeps semantics simple
        const float inv_n = 1.0f / sqrtf(sq[0] + sq[1] + sq[2]);
        p *= inv_n;
        reinterpret_cast<f32x4*>(z + (size_t)b * H)[col] = p;
    } else {
        __builtin_amdgcn_s_barrier();
    }
}

// Kernel 2: 256 blocks = (row i 0..63) x (col-chunk jc 0..3 of 64 cols).
// Thread t: column col = t&63 (global j = jc*64+col), quarter q = t>>6.
// Each thread computes a 192-elem partial dot; LDS-combine to full dots.
// logits in [-2,2] -> exp without max-subtraction is safe (sum <= 255*e^2).
// Block writes: sp[i*4+jc] = sum_j exp(logit_ij) (diag masked);
// jc==0 also writes pairneg[i] = sum_{j>i,j<64} (-logit_ij).
__global__ void row_part_k(const float* __restrict__ z,
                           float* __restrict__ sp,
                           float* __restrict__ pairneg) {
    const int i  = blockIdx.x >> 2;
    const int jc = blockIdx.x & 3;
    const int t  = threadIdx.x;    // 0..255
    const int col = t & 63;
    const int q   = t >> 6;
    const int j   = jc * 64 + col;

    __shared__ float zi[H];
    __shared__ float pd[4][64];

    zi[t]       = z[(size_t)i * H + t];
    zi[t + 256] = z[(size_t)i * H + 256 + t];
    zi[t + 512] = z[(size_t)i * H + 512 + t];
    __syncthreads();

    // partial dot: elems q*192 .. q*192+191 (48 float4)
    const float4* __restrict__ zj4 =
        reinterpret_cast<const float4*>(z + (size_t)j * H) + q * 48;
    const float4* zi4 = reinterpret_cast<const float4*>(zi) + q * 48;
    float d0 = 0.f, d1 = 0.f;
#pragma unroll 8
    for (int k = 0; k < 48; k += 2) {
        float4 a  = zi4[k];     float4 c1 = zj4[k];
        float4 a2 = zi4[k + 1]; float4 c2 = zj4[k + 1];
        d0 += a.x * c1.x + a.y * c1.y + a.z * c1.z + a.w * c1.w;
        d1 += a2.x * c2.x + a2.y * c2.y + a2.z * c2.z + a2.w * c2.w;
    }
    pd[q][col] = d0 + d1;
    __syncthreads();

    if (t < 64) {  // wave 0 finalizes; col == t here
        const float dot = pd[0][t] + pd[1][t] + pd[2][t] + pd[3][t];
        const float logit = dot * 2.0f;  // / TAU
        const float ev = (j == i) ? 0.f : expf(logit);
        float s = waveReduceSum(ev);
        if (t == 0) sp[i * 4 + jc] = s;
        if (jc == 0) {
            const float term = (t > i) ? -logit : 0.f;
            float ts = waveReduceSum(term);
            if (t == 0) pairneg[i] = ts;
        }
    }
}

// Kernel 3: one wave. rowloss_i = (63-i)*log(sum_c sp[i][c]) + pairneg[i].
__global__ void final_k(const float* __restrict__ sp,
                        const float* __restrict__ pairneg,
                        float* __restrict__ out) {
    const int i = threadIdx.x;  // 0..63
    const float s = sp[i * 4] + sp[i * 4 + 1] + sp[i * 4 + 2] + sp[i * 4 + 3];
    const float logden = logf(s);
    const float row = (float)(NSMALL - 1 - i) * logden + pairneg[i];
    float tot = waveReduceSum(row);
    if (i == 0) {
        out[0] = (-2.0f / (float)NSMALL) * (float)(NSMALL - 1) * tot;
    }
}

extern "C" void kernel_launch(void* const* d_in, const int* in_sizes, int n_in,
                              void* d_out, int out_size, void* d_ws, size_t ws_size,
                              hipStream_t stream) {
    const float* lhs  = (const float*)d_in[0];   // [256,512,768] f32
    float* out = (float*)d_out;                  // scalar f32
    float* ws  = (float*)d_ws;

    float* z       = ws;                         // B*H = 196,608 f
    float* sp      = z + (size_t)B * H;          // 64*4 = 256 f
    float* pairneg = sp + NSMALL * 4;            // 64 f

    pool_z_k<<<B, H, 0, stream>>>(lhs, z);
    row_part_k<<<NSMALL * 4, 256, 0, stream>>>(z, sp, pairneg);
    final_k<<<1, 64, 0, stream>>>(sp, pairneg, out);
}